// Round 12
// baseline (51.694 us; speedup 1.0000x reference)
//
#include <hip/hip_runtime.h>
#include <hip/hip_bf16.h>

#define CIN 65
#define LIN 577
#define NSTEP 18      // K = 576 = 18 steps of 32; t_resc is a rank-1 epilogue
#define M_  16384

typedef __bf16 bf16x8 __attribute__((ext_vector_type(8)));
typedef float  f32x4  __attribute__((ext_vector_type(4)));
typedef unsigned short u16x8 __attribute__((ext_vector_type(8)));

// SIG[r] = flatten(rot90(arange(9).reshape(3,3), r)); SIG[(4-g)&3] = sigma_g^{-1}
__constant__ int SIG[4][9] = {
  {0,1,2,3,4,5,6,7,8},
  {2,5,8,1,4,7,0,3,6},
  {8,7,6,5,4,3,2,1,0},
  {6,3,0,7,4,1,8,5,2}};

// ---- kernel 1: W -> Wg[g*18+ks][col 256][32] bf16, linear ------------------
// 73728 work items (4g x 18ks x 256col x 4chunks) -> 144 blocks of 512.
__global__ __launch_bounds__(512) void prep_w(const float* __restrict__ W,
                                              __hip_bfloat16* __restrict__ Wg) {
  int pidx = blockIdx.x * 512 + threadIdx.x;     // 0..73727
  int k8  = pidx & 3;
  int col = (pidx >> 2) & 255;
  int t   = pidx >> 10;                          // g*18 + ks
  int ks  = t % NSTEP, g = t / NSTEP;
  int k   = SIG[(4 - g) & 3][ks >> 1];
  const float* src = W + col * LIN + 1 + k * 64 + (ks & 1) * 32 + k8 * 8;
  u16x8 pk;
#pragma unroll
  for (int e = 0; e < 8; ++e) {
    union { __hip_bfloat16 h; unsigned short u; } cv;
    cv.h = __float2bfloat16(src[e]);
    pk[e] = cv.u;
  }
  *(u16x8*)(Wg + (size_t)pidx * 8) = pk;
}

// ---- kernel 2: FUSED im2col + GEMM + epilogue. One block = (g, b, py). -----
// xs: x slice as bf16 [3 dy][72 slot][8 chunk][8 ch], chunk XOR-swizzled by
// slot (A-fragment ds_read_b128 = bank-spread). B frags global->reg (dense,
// L2-resident Wg), register dbuf. NO mainloop barriers.
__global__ __launch_bounds__(256) void fused_k(const float* __restrict__ x,
                                               const __hip_bfloat16* __restrict__ Wg,
                                               const float* __restrict__ W,
                                               const float* __restrict__ bias,
                                               float* __restrict__ out) {
  __shared__ __align__(16) char smem[28768];
  __hip_bfloat16* xs = (__hip_bfloat16*)smem;      // [3][72][64] @0 (27648 B)
  float* x0  = (float*)(smem + 27648);             // [3][72] f32 (864 B)
  float* Tsh = (float*)(smem + 28512);             // [64] f32

  const int fid = blockIdx.x;
  const int g = fid >> 8, bp = fid & 255;          // same bp across g -> co-XCD
  const int b = bp >> 6, py = bp & 63;
  const int tid = threadIdx.x, wave = tid >> 6, lane = tid & 63;
  const int fr = lane & 15, fq = lane >> 4;
  const int wcb = wave * 64;
  const int brow = bp << 6;                        // b*4096 + py*64

  // B fragments: lane (fr,fq) -> col wcb+j*16+fr, k-bytes fq*16 (dense 1KB/j)
  const __hip_bfloat16* Wgg = Wg + (((size_t)g * NSTEP) << 13)
                                 + (size_t)(wcb + fr) * 32 + fq * 8;
  bf16x8 pA[4], pB[4];
  auto LOADB = [&](bf16x8* dst, int ks) {
#pragma unroll
    for (int j = 0; j < 4; ++j)
      dst[j] = *(const bf16x8*)(Wgg + ((size_t)ks << 13) + j * 512);
  };
  LOADB(pA, 0);   // overlaps LDS staging below

  // zero-fill xs + x0 (28512 B)
  for (int i = tid; i < 1782; i += 256)
    *(f32x4*)(smem + i * 16) = (f32x4){0.f, 0.f, 0.f, 0.f};
  __syncthreads();

  // stage x interior: ch 1..64 x 3 rows x 64 px, f32x4 coalesced -> bf16 LDS
  const float* xb = x + (size_t)b * (CIN * 4096);
#pragma unroll
  for (int r = 0; r < 12; ++r) {
    int idx = r * 256 + tid;                       // 0..3071
    int qq = idx >> 4, v4 = idx & 15;
    int c1 = qq / 3, hyi = qq - c1 * 3;            // c1 = channel-1, hyi = dy
    int hy = py + hyi - 1;
    if (hy >= 0 && hy < 64) {
      f32x4 v = *(const f32x4*)(xb + (1 + c1) * 4096 + hy * 64 + v4 * 4);
#pragma unroll
      for (int e = 0; e < 4; ++e) {
        int s = 4 + v4 * 4 + e;                    // slot = 4 + wx
        xs[(hyi * 72 + s) * 64 + (((c1 >> 3) ^ (s & 7)) << 3) + (c1 & 7)] =
            __float2bfloat16(v[e]);
      }
    }
  }
  if (tid < 48) {                                  // channel-0 slice for t_resc
    int hyi = tid >> 4, v4 = tid & 15;
    int hy = py + hyi - 1;
    if (hy >= 0 && hy < 64)
      *(f32x4*)&x0[hyi * 72 + 4 + v4 * 4] = *(const f32x4*)(xb + hy * 64 + v4 * 4);
  }
  __syncthreads();
  if (tid < 64) {                                  // t_resc per px (rot-invariant)
    float s = 0.f;
#pragma unroll
    for (int m = 0; m < 9; ++m) {
      float tv = fmaxf(x0[(m / 3) * 72 + 3 + tid + (m % 3)], 1.f);
      s += tv * tv;
    }
    Tsh[tid] = sqrtf(s - 8.f);                     // visible after post-loop barrier
  }

  f32x4 acc[4][4] = {};
  auto COMPUTE = [&](int ks, const bf16x8* bf) {
    const int m = ks >> 1, dy = m / 3, dx = m % 3;
    const int sb = 3 + fr + dx;                    // slot for row fr (i adds 16: &7 invariant)
    const int pc = ((ks & 1) * 4 + fq) ^ (sb & 7); // phys chunk (swizzle inverse)
    const char* base = smem + ((dy * 72 + sb) * 8 + pc) * 16;
    bf16x8 af[4];
#pragma unroll
    for (int i = 0; i < 4; ++i)
      af[i] = *(const bf16x8*)(base + i * 2048);   // row i*16+fr
    __builtin_amdgcn_s_setprio(1);
#pragma unroll
    for (int i = 0; i < 4; ++i)
#pragma unroll
      for (int j = 0; j < 4; ++j)
        acc[i][j] = __builtin_amdgcn_mfma_f32_16x16x32_bf16(af[i], bf[j], acc[i][j], 0, 0, 0);
    __builtin_amdgcn_s_setprio(0);
  };

#pragma unroll
  for (int kp = 0; kp < NSTEP; kp += 2) {          // both halves share tap m
    LOADB(pB, kp + 1);
    COMPUTE(kp, pA);
    if (kp + 2 < NSTEP) LOADB(pA, kp + 2);
    COMPUTE(kp + 1, pB);
  }
  __syncthreads();                                 // xs dead; Tsh visible

  // epilogue: y = acc + bias + t*W[:,0]; store y (o!=0); fused Lorentz norm
  float* Ps = (float*)smem;                        // [64][4], aliases xs
  float bo[4], w0v[4]; int oc[4];
#pragma unroll
  for (int j = 0; j < 4; ++j) {
    oc[j]  = wcb + j * 16 + fr;
    bo[j]  = bias[oc[j]];
    w0v[j] = W[oc[j] * LIN];
  }
#pragma unroll
  for (int i = 0; i < 4; ++i) {
#pragma unroll
    for (int rr = 0; rr < 4; ++rr) {
      int rl = i * 16 + fq * 4 + rr;
      int row = brow + rl;
      size_t obase = ((size_t)(((row >> 12) * 4 + g) * 4096 + (row & 4095)) << 8);
      float tval = Tsh[rl];
      float s = 0.f;
#pragma unroll
      for (int j = 0; j < 4; ++j) {
        float y = acc[i][j][rr] + bo[j] + tval * w0v[j];
        if (oc[j] != 0) { s += y * y; out[obase + oc[j]] = y; }
      }
      s += __shfl_xor(s, 1); s += __shfl_xor(s, 2);
      s += __shfl_xor(s, 4); s += __shfl_xor(s, 8);
      if (fr == 0) Ps[rl * 4 + wave] = s;
    }
  }
  __syncthreads();
  if (tid < 64) {
    int row = brow + tid;
    float s = Ps[tid * 4] + Ps[tid * 4 + 1] + Ps[tid * 4 + 2] + Ps[tid * 4 + 3] + 1.0f;
    out[(size_t)(((row >> 12) * 4 + g) * 4096 + (row & 4095)) << 8] = sqrtf(s);
  }
}

extern "C" void kernel_launch(void* const* d_in, const int* in_sizes, int n_in,
                              void* d_out, int out_size, void* d_ws, size_t ws_size,
                              hipStream_t stream) {
  const float* x    = (const float*)d_in[0];
  const float* W    = (const float*)d_in[1];
  const float* bias = (const float*)d_in[2];
  float* out = (float*)d_out;

  __hip_bfloat16* Wg = (__hip_bfloat16*)d_ws;      // 72*256*32*2 = 1179648 B

  prep_w <<<144, 512, 0, stream>>>(W, Wg);
  fused_k<<<1024, 256, 0, stream>>>(x, Wg, W, bias, out);
}

// Round 13
// 50.102 us; speedup vs baseline: 1.0318x; 1.0318x over previous
//
#include <hip/hip_runtime.h>
#include <hip/hip_bf16.h>

#define CIN 65
#define LIN 577
#define NSTEP 18      // K = 576 = 18 steps of 32; t_resc is a rank-1 epilogue
#define M_  16384

typedef __bf16 bf16x8 __attribute__((ext_vector_type(8)));
typedef float  f32x4  __attribute__((ext_vector_type(4)));
typedef unsigned short u16x8 __attribute__((ext_vector_type(8)));

// SIG[r] = flatten(rot90(arange(9).reshape(3,3), r)); SIG[(4-g)&3] = sigma_g^{-1}
__constant__ int SIG[4][9] = {
  {0,1,2,3,4,5,6,7,8},
  {2,5,8,1,4,7,0,3,6},
  {8,7,6,5,4,3,2,1,0},
  {6,3,0,7,4,1,8,5,2}};

// XOR mask for the 4 16B-chunks of a 64B LDS row (2-way max bank aliasing = free)
__device__ __forceinline__ int swzm(int r) { return (r ^ (r >> 2)) & 3; }

// ---- kernel 1 (fused): blocks [0,256): im2col -> A[q 72][row 16384][8] + T
//                        blocks [256,400): W -> Wg[g*18+ks][col 256][32] bf16
__global__ __launch_bounds__(512) void prep_k(const float* __restrict__ x,
                                              const float* __restrict__ W,
                                              __hip_bfloat16* __restrict__ A,
                                              __hip_bfloat16* __restrict__ Wg,
                                              float* __restrict__ T) {
  __shared__ float lds[CIN * 3 * 72];   // [c][dy][slot 4+u], u = x-pos in [-1,64]
  const int tid = threadIdx.x;
  if (blockIdx.x >= 256) {              // ---- weight prep branch ----
    int pidx = (blockIdx.x - 256) * 512 + tid;   // 0..73727
    int jc  = pidx & 3;
    int col = (pidx >> 2) & 255;
    int t   = pidx >> 10;               // g*18 + ks
    int ks  = t % NSTEP, g = t / NSTEP;
    int k   = SIG[(4 - g) & 3][ks >> 1];
    const float* src = W + col * LIN + 1 + k * 64 + (ks & 1) * 32 + jc * 8;
    u16x8 pk;
#pragma unroll
    for (int e = 0; e < 8; ++e) {
      union { __hip_bfloat16 h; unsigned short u; } cv;
      cv.h = __float2bfloat16(src[e]);
      pk[e] = cv.u;
    }
    *(u16x8*)(Wg + (size_t)pidx * 8) = pk;
    return;
  }
  // ---- im2col branch ----
  const int b = blockIdx.x >> 6, py = blockIdx.x & 63;
  const float* xb = x + (size_t)b * (CIN * 4096);
  for (int i = tid; i < CIN * 3 * 18; i += 512)
    *(f32x4*)&lds[i * 4] = (f32x4){0.f, 0.f, 0.f, 0.f};
  __syncthreads();
  for (int i = tid; i < CIN * 3 * 16; i += 512) {
    int pr = i >> 4, j = i & 15;
    int c = pr / 3, dy = pr - c * 3;
    int hy = py + dy - 1;
    if (hy >= 0 && hy < 64)
      *(f32x4*)&lds[c * 216 + dy * 72 + 4 + j * 4] =
          *(const f32x4*)(xb + c * 4096 + hy * 64 + j * 4);
  }
  __syncthreads();

  const int wave = tid >> 6, px = tid & 63;
  const int rowid = (blockIdx.x << 6) | px;
#pragma unroll
  for (int qi = 0; qi < 9; ++qi) {
    int q = wave * 9 + qi;               // q = m*8 + cb8 (chunk of 8 channels)
    int m = q >> 3, cb8 = q & 7;
    int dy = m / 3, dx = m - dy * 3;
    const float* src = &lds[(1 + cb8 * 8) * 216 + dy * 72 + 3 + dx + px];
    u16x8 pk;
#pragma unroll
    for (int e = 0; e < 8; ++e) {
      union { __hip_bfloat16 h; unsigned short u; } cv;
      cv.h = __float2bfloat16(src[e * 216]);
      pk[e] = cv.u;
    }
    *(u16x8*)(A + ((size_t)q * M_ + rowid) * 8) = pk;   // dense 16B/lane
  }
  if (wave == 0) {   // t_resc (rotation-invariant)
    float s = 0.f;
#pragma unroll
    for (int m = 0; m < 9; ++m) {
      float t = fmaxf(lds[(m / 3) * 72 + 3 + (m % 3) + px], 1.f);
      s += t * t;
    }
    T[rowid] = sqrtf(s - 8.f);
  }
}

// ---- kernel 2: GEMM BM=64 BN=256 BK=32, 512 thr, grid 1024, 3 blocks/CU ---
__device__ __forceinline__ void async_cp16(const void* g, void* ldsbase) {
  __builtin_amdgcn_global_load_lds(
      (const __attribute__((address_space(1))) void*)g,
      (__attribute__((address_space(3))) void*)ldsbase, 16, 0, 0);
}

__global__ __launch_bounds__(512, 6) void gemm_k(const __hip_bfloat16* __restrict__ A,
                                                 const __hip_bfloat16* __restrict__ Wg,
                                                 const float* __restrict__ W,
                                                 const float* __restrict__ bias,
                                                 const float* __restrict__ T,
                                                 float* __restrict__ out) {
  // A0 @0 (4K) | A1 @4K | B0 @8K (16K) | B1 @24K | Tsh @40960 | Ps @41216
  __shared__ __align__(16) char smem[42240];
  const int fid = blockIdx.x;
  const int lid = ((fid & 7) << 7) | (fid >> 3);   // per-XCD: 32 rb x 4 g, bijective
  const int g = lid & 3, rb = lid >> 2;
  const int brow = rb << 6;
  const int tid = threadIdx.x, wave = tid >> 6, lane = tid & 63;
  const int fr = lane & 15, fq = lane >> 4;
  const int wr = (wave >> 2) * 32, wcb = (wave & 3) * 64;

  float* Tsh = (float*)(smem + 40960);
  float* Ps  = (float*)(smem + 41216);
  if (tid < 64) Tsh[tid] = T[brow + tid];   // covered by first __syncthreads

  // staging constants (LDS dest linear; global source chunk-permuted, rule #21)
  const int arow = tid >> 2;                       // A: tid<256, 1 chunk
  const int alc  = (tid & 3) ^ swzm(arow);
  const int bc0  = tid >> 2, bl0 = (tid & 3) ^ swzm(bc0);     // B: 2 chunks
  const int bc1  = 128 + (tid >> 2), bl1 = (tid & 3) ^ swzm(bc1);
  const __hip_bfloat16* Wgg = Wg + ((size_t)(g * NSTEP) << 13);

  auto STAGE = [&](int buf, int ks) {
    if (tid < 256)                                  // wave-uniform guard (waves 0-3)
      async_cp16(A + (((size_t)(ks * 4 + alc) * M_ + brow + arow) << 3),
                 smem + buf * 4096 + wave * 1024);
    const __hip_bfloat16* bs = Wgg + ((size_t)ks << 13);
    char* bl = smem + 8192 + buf * 16384 + wave * 1024;
    async_cp16(bs + bc0 * 32 + bl0 * 8, bl);
    async_cp16(bs + bc1 * 32 + bl1 * 8, bl + 8192);
  };

  f32x4 acc[2][4] = {};
  auto COMPUTE = [&](int buf) {
    const char* Ab = smem + buf * 4096;
    const char* Bb = smem + 8192 + buf * 16384;
    bf16x8 af[2], bf[4];
#pragma unroll
    for (int i = 0; i < 2; ++i) {
      int r = wr + i * 16 + fr;
      af[i] = *(const bf16x8*)(Ab + r * 64 + ((fq ^ swzm(r)) << 4));
    }
#pragma unroll
    for (int j = 0; j < 4; ++j) {
      int c = wcb + j * 16 + fr;
      bf[j] = *(const bf16x8*)(Bb + c * 64 + ((fq ^ swzm(c)) << 4));
    }
    __builtin_amdgcn_s_setprio(1);
#pragma unroll
    for (int i = 0; i < 2; ++i)
#pragma unroll
      for (int j = 0; j < 4; ++j)
        acc[i][j] = __builtin_amdgcn_mfma_f32_16x16x32_bf16(af[i], bf[j], acc[i][j], 0, 0, 0);
    __builtin_amdgcn_s_setprio(0);
  };

  STAGE(0, 0);
  __syncthreads();
  for (int ks = 0; ks < NSTEP; ++ks) {
    if (ks + 1 < NSTEP) STAGE((ks + 1) & 1, ks + 1);
    COMPUTE(ks & 1);
    __syncthreads();
  }

  // epilogue: y = acc + bias + t*W[:,0]; store y (o!=0); fused Lorentz norm
  float bo[4], w0v[4]; int oc[4];
#pragma unroll
  for (int j = 0; j < 4; ++j) {
    oc[j]  = wcb + j * 16 + fr;
    bo[j]  = bias[oc[j]];
    w0v[j] = W[oc[j] * LIN];
  }
#pragma unroll
  for (int i = 0; i < 2; ++i) {
#pragma unroll
    for (int rr = 0; rr < 4; ++rr) {
      int rl = wr + i * 16 + fq * 4 + rr;
      int row = brow + rl;
      size_t obase = ((size_t)(((row >> 12) * 4 + g) * 4096 + (row & 4095)) << 8);
      float tval = Tsh[rl];
      float s = 0.f;
#pragma unroll
      for (int j = 0; j < 4; ++j) {
        float y = acc[i][j][rr] + bo[j] + tval * w0v[j];
        if (oc[j] != 0) { s += y * y; out[obase + oc[j]] = y; }
      }
      s += __shfl_xor(s, 1); s += __shfl_xor(s, 2);
      s += __shfl_xor(s, 4); s += __shfl_xor(s, 8);
      if (fr == 0) Ps[rl * 4 + (wave & 3)] = s;
    }
  }
  __syncthreads();
  if (tid < 64) {
    int row = brow + tid;
    float s = Ps[tid * 4] + Ps[tid * 4 + 1] + Ps[tid * 4 + 2] + Ps[tid * 4 + 3] + 1.0f;
    out[(size_t)(((row >> 12) * 4 + g) * 4096 + (row & 4095)) << 8] = sqrtf(s);
  }
}

extern "C" void kernel_launch(void* const* d_in, const int* in_sizes, int n_in,
                              void* d_out, int out_size, void* d_ws, size_t ws_size,
                              hipStream_t stream) {
  const float* x    = (const float*)d_in[0];
  const float* W    = (const float*)d_in[1];
  const float* bias = (const float*)d_in[2];
  float* out = (float*)d_out;

  char* ws = (char*)d_ws;
  __hip_bfloat16* Wg = (__hip_bfloat16*)ws;                 // 73728*8*2 = 1179648 B
  float*          T  = (float*)(ws + 1179648);              // 65536 B
  __hip_bfloat16* A  = (__hip_bfloat16*)(ws + 1245184);     // 72*16384*8*2 = 18874368 B

  prep_k<<<400, 512, 0, stream>>>(x, W, A, Wg, T);
  gemm_k<<<1024, 512, 0, stream>>>(A, Wg, W, bias, T, out);
}